// Round 6
// baseline (2348.579 us; speedup 1.0000x reference)
//
#include <hip/hip_runtime.h>

typedef unsigned short u16;
typedef unsigned int   u32;
typedef unsigned long long u64;
typedef __attribute__((ext_vector_type(8))) short bf16x8;
typedef __attribute__((ext_vector_type(4))) float f32x4;

#define GK 768            // K dim of all GEMMs
#define NSTEP 196
#define HSTEP 49152       // 64*768 elements per step slab
#define PWG 24            // workgroups per batch-group (8 groups x 24 active)
#define NBLK 256          // launched workgroups (claim protocol)
#define FLAG0 32          // fast step-flags base (sc0 stores, XCD-local L2)
#define MIR0 512          // agent-scope mirror flags base (liveness rescue)
#define SENT (-7777)      // self-test sentinel (< any step value)

__device__ __forceinline__ u16 f2bf(float f) {
    u32 u = __float_as_uint(f);
    u = (u + 0x7fffu + ((u >> 16) & 1u)) >> 16;
    return (u16)u;
}
__device__ __forceinline__ float bf2f(u16 h) { return __uint_as_float(((u32)h) << 16); }

// ---------------------------------------------------------------------------
// fp32 -> bf16 convert for x, Wx, Wp; block 0 zeros all 1024 flag ints.
// ---------------------------------------------------------------------------
__global__ __launch_bounds__(256) void cvt_kernel(
    const float4* __restrict__ x, const float4* __restrict__ wx,
    const float4* __restrict__ wp,
    u32* __restrict__ xb, u32* __restrict__ wxb, u32* __restrict__ wpb,
    int* __restrict__ flags)
{
    const int N1 = 9633792 / 4, N2 = 1769472 / 4;
    int i = blockIdx.x * 256 + threadIdx.x;
    if (blockIdx.x == 0) {
        flags[threadIdx.x]       = 0;
        flags[256 + threadIdx.x] = 0;
        flags[512 + threadIdx.x] = 0;
        flags[768 + threadIdx.x] = 0;
    }
    const float4* src; u32* dst; int off;
    if (i < N1)            { src = x;  dst = xb;  off = i; }
    else if (i < N1 + N2)  { src = wx; dst = wxb; off = i - N1; }
    else                   { src = wp; dst = wpb; off = i - N1 - N2; }
    float4 v = src[off];
    u32 lo = (u32)f2bf(v.x) | ((u32)f2bf(v.y) << 16);
    u32 hi = (u32)f2bf(v.z) | ((u32)f2bf(v.w) << 16);
    dst[(size_t)off * 2]     = lo;
    dst[(size_t)off * 2 + 1] = hi;
}

// ---------------------------------------------------------------------------
// GEMM: out[M][N] = A[M][K] @ B[N][K]^T   (A,B bf16 row-major K-contiguous)
// ---------------------------------------------------------------------------
template<int MODE>
__global__ __launch_bounds__(256) void gemm_bt(
    const u16* __restrict__ A, const u16* __restrict__ B,
    const float* __restrict__ bias, void* __restrict__ outv)
{
    __shared__ u16 As[128 * 40];
    __shared__ u16 Bs[128 * 40];
    const int tid  = threadIdx.x;
    const int lane = tid & 63;
    const int wv   = tid >> 6;
    const int m0 = blockIdx.y * 128;
    const int n0 = blockIdx.x * 128;
    const int wm = (wv & 1) * 64;
    const int wn = (wv >> 1) * 64;

    f32x4 acc[4][4];
#pragma unroll
    for (int i = 0; i < 4; ++i)
#pragma unroll
        for (int j = 0; j < 4; ++j) acc[i][j] = (f32x4){0.f, 0.f, 0.f, 0.f};

    const int r0 = tid >> 2, q0 = tid & 3;
    const u16* gA0 = A + (size_t)(m0 + r0)      * GK + q0 * 8;
    const u16* gA1 = A + (size_t)(m0 + r0 + 64) * GK + q0 * 8;
    const u16* gB0 = B + (size_t)(n0 + r0)      * GK + q0 * 8;
    const u16* gB1 = B + (size_t)(n0 + r0 + 64) * GK + q0 * 8;
    u16* sA0 = As + r0 * 40 + q0 * 8;
    u16* sA1 = As + (r0 + 64) * 40 + q0 * 8;
    u16* sB0 = Bs + r0 * 40 + q0 * 8;
    u16* sB1 = Bs + (r0 + 64) * 40 + q0 * 8;

    const int fr = lane & 15, fq = lane >> 4;
    const u16* fA = As + (wm + fr) * 40 + fq * 8;
    const u16* fB = Bs + (wn + fr) * 40 + fq * 8;

    for (int kt = 0; kt < GK / 32; ++kt) {
        uint4 a0 = *(const uint4*)(gA0 + kt * 32);
        uint4 a1 = *(const uint4*)(gA1 + kt * 32);
        uint4 b0 = *(const uint4*)(gB0 + kt * 32);
        uint4 b1 = *(const uint4*)(gB1 + kt * 32);
        __syncthreads();
        *(uint4*)sA0 = a0; *(uint4*)sA1 = a1;
        *(uint4*)sB0 = b0; *(uint4*)sB1 = b1;
        __syncthreads();
        bf16x8 af[4], bfr[4];
#pragma unroll
        for (int mi = 0; mi < 4; ++mi) af[mi]  = *(const bf16x8*)(fA + mi * 16 * 40);
#pragma unroll
        for (int ni = 0; ni < 4; ++ni) bfr[ni] = *(const bf16x8*)(fB + ni * 16 * 40);
#pragma unroll
        for (int mi = 0; mi < 4; ++mi)
#pragma unroll
            for (int ni = 0; ni < 4; ++ni)
                acc[mi][ni] = __builtin_amdgcn_mfma_f32_16x16x32_bf16(
                    af[mi], bfr[ni], acc[mi][ni], 0, 0, 0);
    }

    if (MODE == 1) {
        u16* out = (u16*)outv;
#pragma unroll
        for (int mi = 0; mi < 4; ++mi) {
#pragma unroll
            for (int ni = 0; ni < 4; ++ni) {
                int col = n0 + wn + ni * 16 + fr;
                float bv = bias[col];
#pragma unroll
                for (int r = 0; r < 4; ++r) {
                    int m = m0 + wm + mi * 16 + fq * 4 + r;
                    int b = m / 196;
                    int nn = m - b * 196;
                    u16 hv = f2bf(acc[mi][ni][r] + bv);
                    int other = __shfl_xor((int)hv, 1, 64);
                    if (!(lane & 1)) {
                        u32 packed = (u32)hv | (((u32)(u16)other) << 16);
                        size_t eidx = ((size_t)nn * 64 + (size_t)b) * 2304 + (size_t)col;
                        *((u32*)out + (eidx >> 1)) = packed;
                    }
                }
            }
        }
    } else {
        float* out = (float*)outv;
#pragma unroll
        for (int mi = 0; mi < 4; ++mi) {
#pragma unroll
            for (int ni = 0; ni < 4; ++ni) {
                int col = n0 + wn + ni * 16 + fr;
#pragma unroll
                for (int r = 0; r < 4; ++r) {
                    int m = m0 + wm + mi * 16 + fq * 4 + r;   // m = n*64 + b
                    int b = m & 63;
                    int nn = m >> 6;
                    out[((size_t)b * 196 + nn) * 768 + col] = acc[mi][ni][r];
                }
            }
        }
    }
}

// ---------------------------------------------------------------------------
// Primitives. sc0 load: L1-bypass, L2-served. sc0 store: write-through to L2.
// Neither is assumed coherent beyond one XCD's L2 -- the SELF-TEST verifies
// exactly the producer->consumer visibility the fast path needs; any group
// failing it runs the proven agent-scope protocol instead.
// ---------------------------------------------------------------------------
__device__ __forceinline__ int poll_load_sc0(const int* p) {
    int v;
    asm volatile("global_load_dword %0, %1, off sc0\n\t"
                 "s_waitcnt vmcnt(0)"
                 : "=v"(v) : "v"(p) : "memory");
    return v;
}
__device__ __forceinline__ void store_sc0(int* p, int v) {
    asm volatile("global_store_dword %0, %1, off sc0"
                 :: "v"(p), "v"(v) : "memory");
}
__device__ __forceinline__ void store_sc0_u64(u64* p, u64 v) {
    asm volatile("global_store_dwordx2 %0, %1, off sc0"
                 :: "v"(p), "v"(v) : "memory");
}
__device__ __forceinline__ int agent_load(const int* p) {
    return __hip_atomic_load(p, __ATOMIC_RELAXED, __HIP_MEMORY_SCOPE_AGENT);
}

// ---------------------------------------------------------------------------
// Batch-split GRU recurrence (FAST = self-test-verified L2-local protocol;
// !FAST = agent-scope protocol, proven). Group g owns batches [g*8, g*8+8);
// 24 WGs x 32 h-channels. Wh slice in registers. 6 waves = 3 gates x 2
// K-halves, each a 16x32x384 MFMA chain; K-halves reduced in LDS; gate
// threads (tid<256) do pointwise GRU + publish. FAST poll: wave 0 only,
// s_sleep backoff (cuts same-line L2 poll traffic ~20x), sticky bounded
// rescue to agent mirror flags -- cannot hang.
// ---------------------------------------------------------------------------
template<bool FAST>
__device__ void recur_run(
    int g, int s, int tid,
    const u16* __restrict__ xz, const float* __restrict__ Wh,
    const float* __restrict__ bh, u16* __restrict__ hsx, int* flags,
    float* hzs)
{
    const int lane = tid & 63;
    const int wv   = tid >> 6;          // 0..5
    const int kh   = wv & 1;            // K half (384 each)
    const int np   = wv >> 1;           // gate index 0..2
    const int fr   = lane & 15, fq = lane >> 4;
    const int c0   = s * 32;            // this WG's h-channel base
    const int B0   = g * 8;             // this group's batch base

    // ---- one-time: Wh slice -> B-frags in registers (bf16) ----
    bf16x8 bfrag[2][12];
#pragma unroll
    for (int j = 0; j < 2; ++j) {
        int row = np * 768 + c0 + j * 16 + fr;
        const float* wp = Wh + (size_t)row * 768 + kh * 384 + fq * 8;
#pragma unroll
        for (int kk = 0; kk < 12; ++kk) {
            float4 f0 = *(const float4*)(wp + kk * 32);
            float4 f1 = *(const float4*)(wp + kk * 32 + 4);
            bf16x8 b;
            b[0] = (short)f2bf(f0.x); b[1] = (short)f2bf(f0.y);
            b[2] = (short)f2bf(f0.z); b[3] = (short)f2bf(f0.w);
            b[4] = (short)f2bf(f1.x); b[5] = (short)f2bf(f1.y);
            b[6] = (short)f2bf(f1.z); b[7] = (short)f2bf(f1.w);
            bfrag[j][kk] = b;
        }
    }

    // gate-phase constants: thread t<256 -> (batch gb, channel gi)
    const int gb = tid >> 5, gi = tid & 31;
    const int gc = c0 + gi;
    float bh0 = 0.f, bh1 = 0.f, bh2 = 0.f, hold = 0.f;
    if (tid < 256) { bh0 = bh[gc]; bh1 = bh[768 + gc]; bh2 = bh[1536 + gc]; }

    // poll mapping: surject 64 lanes onto the group's 24 flags (one line)
    int fl = lane;
    if (fl >= 48) fl -= 48; else if (fl >= 24) fl -= 24;
    int* const myflag      = &flags[FLAG0 + g * 32 + s];
    int* const mymir       = &flags[MIR0  + g * 32 + s];
    const int* const pollf = &flags[FLAG0 + g * 32 + fl];
    const int* const pollm = &flags[MIR0  + g * 32 + fl];

    // preload xz for step 0
    float xgn0 = 0.f, xgn1 = 0.f, xgn2 = 0.f;
    if (tid < 256) {
        size_t xoff = (size_t)(B0 + gb) * 2304 + gc;
        xgn0 = bf2f(xz[xoff]);
        xgn1 = bf2f(xz[xoff + 768]);
        xgn2 = bf2f(xz[xoff + 1536]);
    }

    bool slow = !FAST;

    for (int n = 0; n < NSTEP; ++n) {
        const float xg0 = xgn0, xg1 = xgn1, xg2 = xgn2;   // prefetched

        f32x4 acc0 = (f32x4){0.f, 0.f, 0.f, 0.f};
        f32x4 acc1 = (f32x4){0.f, 0.f, 0.f, 0.f};

        if (n > 0) {
            if (FAST) {
                // single-poller: wave 0 spins (with backoff), others park at
                // the barrier; release the moment the last flag lands.
                if (tid < 64) {
                    if (!slow) {
                        int tries = 0;
                        for (;;) {
                            int v = poll_load_sc0(pollf);
                            if (__all(v >= n)) break;
                            if (++tries > 1024) { slow = true; break; }
                            __builtin_amdgcn_s_sleep(1);
                        }
                    }
                    if (slow) {
                        for (;;) {
                            int v = agent_load(pollm);
                            if (__all(v >= n)) break;
                            __builtin_amdgcn_s_sleep(2);
                        }
                    }
                }
                __syncthreads();
            } else {
                for (;;) {
                    int v = agent_load(pollf);
                    if (__all(v >= n)) break;
                }
            }
            // A-frags: h[n-1][B0+fr][k]; rows fr>=8 zero (M=8 padded to 16)
            const u16* ap = hsx + (size_t)(n - 1) * HSTEP
                                + (size_t)(B0 + fr) * 768 + kh * 384 + fq * 8;
            const bool arow = fr < 8;
#pragma unroll
            for (int kk = 0; kk < 12; ++kk) {
                bf16x8 a = arow ? *(const bf16x8*)(ap + kk * 32)
                                : (bf16x8){0, 0, 0, 0, 0, 0, 0, 0};
                acc0 = __builtin_amdgcn_mfma_f32_16x16x32_bf16(a, bfrag[0][kk], acc0, 0, 0, 0);
                acc1 = __builtin_amdgcn_mfma_f32_16x16x32_bf16(a, bfrag[1][kk], acc1, 0, 0, 0);
            }
        }

        // prefetch next step's xz (latency hides under LDS/sync/gates)
        if (tid < 256) {
            int np1 = (n + 1 < NSTEP) ? n + 1 : NSTEP - 1;
            size_t xoff = ((size_t)np1 * 64 + (B0 + gb)) * 2304 + gc;
            xgn0 = bf2f(xz[xoff]);
            xgn1 = bf2f(xz[xoff + 768]);
            xgn2 = bf2f(xz[xoff + 1536]);
        }

        // partial h_zrn (per K-half) -> LDS
#pragma unroll
        for (int r = 0; r < 4; ++r) {
            int b = fq * 4 + r;
            if (b < 8) {
                hzs[(kh * 8 + b) * 96 + np * 32 + fr]      = acc0[r];
                hzs[(kh * 8 + b) * 96 + np * 32 + 16 + fr] = acc1[r];
            }
        }
        __syncthreads();

        if (tid < 256) {
            float h0 = hzs[gb * 96 + gi]      + hzs[(8 + gb) * 96 + gi]      + bh0;
            float h1 = hzs[gb * 96 + 32 + gi] + hzs[(8 + gb) * 96 + 32 + gi] + bh1;
            float h2 = hzs[gb * 96 + 64 + gi] + hzs[(8 + gb) * 96 + 64 + gi] + bh2;
            float z   = 1.f / (1.f + __expf(-(xg0 + h0)));
            float rr2 = 1.f / (1.f + __expf(-(xg1 + h1)));
            float pre = xg2 + rr2 * h2;
            float e2  = __expf(-2.f * pre);
            float nc  = (1.f - e2) / (1.f + e2);
            float hnew = (1.f - z) * nc + z * hold;
            hold = hnew;

            // pack 4 channels -> one 8B store per 4 threads
            u16 hv = f2bf(hnew);
            u32 other = ((u32)__shfl_xor((int)hv, 1, 64)) & 0xffffu;
            u32 v01 = (u32)hv | (other << 16);
            u32 v23 = (u32)__shfl_xor((int)v01, 2, 64);
            if ((tid & 3) == 0) {
                u64 q = (u64)v01 | ((u64)v23 << 32);
                size_t ofs = (size_t)n * HSTEP + (size_t)(B0 + gb) * 768 + gc;
                u64* p = (u64*)(hsx + ofs);
                if (FAST) {
                    store_sc0_u64(p, q);   // explicit write-through to L2
                } else {
                    __hip_atomic_store(p, q, __ATOMIC_RELAXED, __HIP_MEMORY_SCOPE_AGENT);
                }
            }
        }
        asm volatile("s_waitcnt vmcnt(0)" ::: "memory");  // h visible before flag
        __syncthreads();
        if (FAST) {
            if (tid == 0)
                store_sc0(myflag, n + 1);                           // fast (L2)
            else if (tid == 64)
                __hip_atomic_store(mymir, n + 1, __ATOMIC_RELAXED,
                                   __HIP_MEMORY_SCOPE_AGENT);       // rescue (L3)
        } else {
            if (tid == 0)
                __hip_atomic_store(myflag, n + 1, __ATOMIC_RELAXED,
                                   __HIP_MEMORY_SCOPE_AGENT);
        }
    }
}

// ---------------------------------------------------------------------------
// Persistent cooperative kernel. Claim -> barrier -> group formation from
// measured per-XCD counts -> EMPIRICAL sc0 self-test per group -> dispatch.
// flags: [0..7] claim counters, [15] barrier, [16..23] per-group fail counts,
// [24..31] per-group vote counters, [FLAG0+g*32+s] fast flags (sentinel'd),
// [MIR0+g*32+s] agent mirrors.
// Timing bands (diagnostic, only on degraded paths): any group failed the
// self-test -> +1 ms; G<8 -> +2 ms.
// ---------------------------------------------------------------------------
__global__ __launch_bounds__(384) void recur2_kernel(
    const u16* __restrict__ xz, const float* __restrict__ Wh,
    const float* __restrict__ bh, u16* __restrict__ hsx, int* flags)
{
    __shared__ float hzs[2 * 8 * 96];
    __shared__ int sh_mode, sh_g, sh_s, sh_ok, sh_local;
    const int tid = threadIdx.x;

    __builtin_amdgcn_fence(__ATOMIC_ACQUIRE, "agent");

    if (tid == 0) {
        u32 xcc = 0;
        asm volatile("s_getreg_b32 %0, hwreg(HW_REG_XCC_ID)" : "=s"(xcc));
        const int my_xcd = (int)(xcc & 7u);
        const int slot = __hip_atomic_fetch_add(&flags[my_xcd], 1, __ATOMIC_ACQ_REL,
                                                __HIP_MEMORY_SCOPE_AGENT);
        __hip_atomic_fetch_add(&flags[15], 1, __ATOMIC_ACQ_REL,
                               __HIP_MEMORY_SCOPE_AGENT);
        while (__hip_atomic_load(&flags[15], __ATOMIC_ACQUIRE,
                                 __HIP_MEMORY_SCOPE_AGENT) < NBLK)
            __builtin_amdgcn_s_sleep(1);
        int G = 0, pre = 0, myg = 0;
        for (int x = 0; x < 8; ++x) {
            int c  = agent_load(&flags[x]);
            int gx = c / PWG;
            if (x < my_xcd) pre += gx;
            if (x == my_xcd) myg = gx;
            G += gx;
        }
        const int grp = pre + slot / PWG;
        const bool act = (slot < myg * PWG) && (grp < 8);
        sh_mode = (G >= 8) ? (act ? 1 : 2) : 0;
        sh_g = grp;
        sh_s = slot % PWG;
    }
    __syncthreads();
    const int mode = sh_mode;
    const int g = sh_g, s = sh_s;

    if (mode == 1) {
        // -------- empirical locality self-test (fast-path primitives) -----
        int* const myflag      = &flags[FLAG0 + g * 32 + s];
        int fl = tid & 63;
        if (fl >= 48) fl -= 48; else if (fl >= 24) fl -= 24;
        const int* const pollf = &flags[FLAG0 + g * 32 + fl];

        if (tid == 0) store_sc0(myflag, SENT);
        bool stest_ok = false;
        if (tid < 64) {
            for (int t = 0; t < 2048; ++t) {
                int v = poll_load_sc0(pollf);
                if (__all(v == SENT)) { stest_ok = true; break; }
                __builtin_amdgcn_s_sleep(1);
            }
        }
        if (tid == 0) {
            if (!stest_ok)
                __hip_atomic_fetch_add(&flags[16 + g], 1, __ATOMIC_ACQ_REL,
                                       __HIP_MEMORY_SCOPE_AGENT);
            __hip_atomic_fetch_add(&flags[24 + g], 1, __ATOMIC_ACQ_REL,
                                   __HIP_MEMORY_SCOPE_AGENT);
            while (agent_load(&flags[24 + g]) < PWG) __builtin_amdgcn_s_sleep(2);
            sh_local = (agent_load(&flags[16 + g]) == 0) ? 1 : 0;
            // diagnostic marker: g0s0 reports if ANY group failed (+1 ms)
            if (g == 0 && s == 0) {
                bool anyfail = false;
                for (int x = 0; x < 8; ++x) {
                    while (agent_load(&flags[24 + x]) < PWG) __builtin_amdgcn_s_sleep(2);
                    anyfail |= (agent_load(&flags[16 + x]) > 0);
                }
                if (anyfail) {
                    u64 t0 = clock64();
                    while (clock64() - t0 < 2400000ull) __builtin_amdgcn_s_sleep(8);
                }
            }
        }
        __syncthreads();
        if (sh_local)
            recur_run<true >(g, s, tid, xz, Wh, bh, hsx, flags, hzs);
        else
            recur_run<false>(g, s, tid, xz, Wh, bh, hsx, flags, hzs);
    } else if (mode == 0) {
        // pathological placement: device-scope protocol, any layout (proven)
        const int bid = blockIdx.x;
        if (bid < 8 * PWG) {
            recur_run<false>(bid & 7, bid >> 3, tid, xz, Wh, bh, hsx, flags, hzs);
        } else if (bid == NBLK - 1 && tid == 0) {
            // diagnostic marker: G<8 (+2 ms)
            u64 t0 = clock64();
            while (clock64() - t0 < 4800000ull) __builtin_amdgcn_s_sleep(8);
        }
    }
    // mode == 2: surplus WG, idle
}

// ---------------------------------------------------------------------------
extern "C" void kernel_launch(void* const* d_in, const int* in_sizes, int n_in,
                              void* d_out, int out_size, void* d_ws, size_t ws_size,
                              hipStream_t stream)
{
    const float* x  = (const float*)d_in[0];
    const float* Wx = (const float*)d_in[1];
    const float* bx = (const float*)d_in[2];
    const float* Wh = (const float*)d_in[3];
    const float* bh = (const float*)d_in[4];
    const float* Wp = (const float*)d_in[5];
    float* out = (float*)d_out;

    char* ws = (char*)d_ws;
    size_t off = 0;
    auto wsalloc = [&](size_t bytes) -> void* {
        void* p = ws + off;
        off += (bytes + 255) & ~(size_t)255;
        return p;
    };
    u16* xb   = (u16*)wsalloc(9633792ull * 2);            // x bf16 [12544][768]
    u16* wxb  = (u16*)wsalloc(1769472ull * 2);            // Wx bf16 [2304][768]
    u16* wpb  = (u16*)wsalloc(589824ull * 2);             // Wp bf16 [768][768]
    u16* xzrn = (u16*)wsalloc(196ull * 64 * 2304 * 2);    // [n][b][3C] bf16
    u16* hsx  = (u16*)wsalloc(196ull * 64 * 768 * 2);     // [n][b][C] bf16
    int* flags = (int*)wsalloc(4096);                     // 1024 ints

    // 1) converts (+ zero all flag zones)
    cvt_kernel<<<11712, 256, 0, stream>>>(
        (const float4*)x, (const float4*)Wx, (const float4*)Wp,
        (u32*)xb, (u32*)wxb, (u32*)wpb, flags);

    // 2) x_zrn = seq @ Wx^T + bx  ->  [n][b][3C] bf16
    gemm_bt<1><<<dim3(18, 98), 256, 0, stream>>>(xb, wxb, bx, (void*)xzrn);

    // 3) cooperative batch-split recurrence (self-test-verified fast path)
    {
        const u16* a0 = xzrn; const float* a1 = Wh; const float* a2 = bh;
        u16* a3 = hsx; int* a4 = flags;
        void* args[5] = { &a0, &a1, &a2, &a3, &a4 };
        hipLaunchCooperativeKernel((void*)recur2_kernel, dim3(NBLK), dim3(384),
                                   args, 0, stream);
    }

    // 4) y = hsx @ Wp^T -> d_out fp32 (rows m = n*64+b, remapped on store)
    gemm_bt<0><<<dim3(6, 98), 256, 0, stream>>>(hsx, wpb, nullptr, (void*)out);
}

// Round 8
// 1096.237 us; speedup vs baseline: 2.1424x; 2.1424x over previous
//
#include <hip/hip_runtime.h>

typedef unsigned short u16;
typedef unsigned int   u32;
typedef unsigned long long u64;
typedef __attribute__((ext_vector_type(8))) short bf16x8;
typedef __attribute__((ext_vector_type(4))) float f32x4;

#define GK 768            // K dim of all GEMMs
#define NSTEP 196
#define HSTEP 49152       // 64*768 elements per step slab
#define PWG 24            // workgroups per batch-group
#define NGRP 8            // batch groups (8 batches each)
#define FLINE 32          // ints per group flag line (128B)
#define GUARD (1 << 18)   // spin guard: force-exit instead of hanging

__device__ __forceinline__ u16 f2bf(float f) {
    u32 u = __float_as_uint(f);
    u = (u + 0x7fffu + ((u >> 16) & 1u)) >> 16;
    return (u16)u;
}
__device__ __forceinline__ float bf2f(u16 h) { return __uint_as_float(((u32)h) << 16); }

__device__ __forceinline__ int agent_load(const int* p) {
    return __hip_atomic_load(p, __ATOMIC_RELAXED, __HIP_MEMORY_SCOPE_AGENT);
}
__device__ __forceinline__ void agent_store(int* p, int v) {
    __hip_atomic_store(p, v, __ATOMIC_RELAXED, __HIP_MEMORY_SCOPE_AGENT);
}

// ---------------------------------------------------------------------------
// fp32 -> bf16 convert for x, Wx, Wp; block 0 zeros the 256 flag ints
// (8 group lines x 32).
// ---------------------------------------------------------------------------
__global__ __launch_bounds__(256) void cvt_kernel(
    const float4* __restrict__ x, const float4* __restrict__ wx,
    const float4* __restrict__ wp,
    u32* __restrict__ xb, u32* __restrict__ wxb, u32* __restrict__ wpb,
    int* __restrict__ flags)
{
    const int N1 = 9633792 / 4, N2 = 1769472 / 4;
    int i = blockIdx.x * 256 + threadIdx.x;
    if (blockIdx.x == 0) flags[threadIdx.x] = 0;
    const float4* src; u32* dst; int off;
    if (i < N1)            { src = x;  dst = xb;  off = i; }
    else if (i < N1 + N2)  { src = wx; dst = wxb; off = i - N1; }
    else                   { src = wp; dst = wpb; off = i - N1 - N2; }
    float4 v = src[off];
    u32 lo = (u32)f2bf(v.x) | ((u32)f2bf(v.y) << 16);
    u32 hi = (u32)f2bf(v.z) | ((u32)f2bf(v.w) << 16);
    dst[(size_t)off * 2]     = lo;
    dst[(size_t)off * 2 + 1] = hi;
}

// ---------------------------------------------------------------------------
// GEMM: out[M][N] = A[M][K] @ B[N][K]^T   (A,B bf16 row-major K-contiguous)
// MODE 1: += bias[col], bf16 out remapped to [n][b][col] with m = b*196+n
// MODE 0: fp32 out; A rows are m = n*64+b, output row remapped to b*196+n
// ---------------------------------------------------------------------------
template<int MODE>
__global__ __launch_bounds__(256) void gemm_bt(
    const u16* __restrict__ A, const u16* __restrict__ B,
    const float* __restrict__ bias, void* __restrict__ outv)
{
    __shared__ u16 As[128 * 40];
    __shared__ u16 Bs[128 * 40];
    const int tid  = threadIdx.x;
    const int lane = tid & 63;
    const int wv   = tid >> 6;
    const int m0 = blockIdx.y * 128;
    const int n0 = blockIdx.x * 128;
    const int wm = (wv & 1) * 64;
    const int wn = (wv >> 1) * 64;

    f32x4 acc[4][4];
#pragma unroll
    for (int i = 0; i < 4; ++i)
#pragma unroll
        for (int j = 0; j < 4; ++j) acc[i][j] = (f32x4){0.f, 0.f, 0.f, 0.f};

    const int r0 = tid >> 2, q0 = tid & 3;
    const u16* gA0 = A + (size_t)(m0 + r0)      * GK + q0 * 8;
    const u16* gA1 = A + (size_t)(m0 + r0 + 64) * GK + q0 * 8;
    const u16* gB0 = B + (size_t)(n0 + r0)      * GK + q0 * 8;
    const u16* gB1 = B + (size_t)(n0 + r0 + 64) * GK + q0 * 8;
    u16* sA0 = As + r0 * 40 + q0 * 8;
    u16* sA1 = As + (r0 + 64) * 40 + q0 * 8;
    u16* sB0 = Bs + r0 * 40 + q0 * 8;
    u16* sB1 = Bs + (r0 + 64) * 40 + q0 * 8;

    const int fr = lane & 15, fq = lane >> 4;
    const u16* fA = As + (wm + fr) * 40 + fq * 8;
    const u16* fB = Bs + (wn + fr) * 40 + fq * 8;

    for (int kt = 0; kt < GK / 32; ++kt) {
        uint4 a0 = *(const uint4*)(gA0 + kt * 32);
        uint4 a1 = *(const uint4*)(gA1 + kt * 32);
        uint4 b0 = *(const uint4*)(gB0 + kt * 32);
        uint4 b1 = *(const uint4*)(gB1 + kt * 32);
        __syncthreads();
        *(uint4*)sA0 = a0; *(uint4*)sA1 = a1;
        *(uint4*)sB0 = b0; *(uint4*)sB1 = b1;
        __syncthreads();
        bf16x8 af[4], bfr[4];
#pragma unroll
        for (int mi = 0; mi < 4; ++mi) af[mi]  = *(const bf16x8*)(fA + mi * 16 * 40);
#pragma unroll
        for (int ni = 0; ni < 4; ++ni) bfr[ni] = *(const bf16x8*)(fB + ni * 16 * 40);
#pragma unroll
        for (int mi = 0; mi < 4; ++mi)
#pragma unroll
            for (int ni = 0; ni < 4; ++ni)
                acc[mi][ni] = __builtin_amdgcn_mfma_f32_16x16x32_bf16(
                    af[mi], bfr[ni], acc[mi][ni], 0, 0, 0);
    }

    if (MODE == 1) {
        u16* out = (u16*)outv;
#pragma unroll
        for (int mi = 0; mi < 4; ++mi) {
#pragma unroll
            for (int ni = 0; ni < 4; ++ni) {
                int col = n0 + wn + ni * 16 + fr;
                float bv = bias[col];
#pragma unroll
                for (int r = 0; r < 4; ++r) {
                    int m = m0 + wm + mi * 16 + fq * 4 + r;
                    int b = m / 196;
                    int nn = m - b * 196;
                    u16 hv = f2bf(acc[mi][ni][r] + bv);
                    int other = __shfl_xor((int)hv, 1, 64);
                    if (!(lane & 1)) {
                        u32 packed = (u32)hv | (((u32)(u16)other) << 16);
                        size_t eidx = ((size_t)nn * 64 + (size_t)b) * 2304 + (size_t)col;
                        *((u32*)out + (eidx >> 1)) = packed;
                    }
                }
            }
        }
    } else {
        float* out = (float*)outv;
#pragma unroll
        for (int mi = 0; mi < 4; ++mi) {
#pragma unroll
            for (int ni = 0; ni < 4; ++ni) {
                int col = n0 + wn + ni * 16 + fr;
#pragma unroll
                for (int r = 0; r < 4; ++r) {
                    int m = m0 + wm + mi * 16 + fq * 4 + r;   // m = n*64 + b
                    int b = m & 63;
                    int nn = m >> 6;
                    out[((size_t)b * 196 + nn) * 768 + col] = acc[mi][ni][r];
                }
            }
        }
    }
}

// ---------------------------------------------------------------------------
// Batch-split GRU recurrence, agent-scope protocol ONLY (sc0/XCD-local
// communication empirically refuted by R6's sentinel test). Group g = bid/24
// owns batches [g*8, g*8+8); 24 WGs x 32 h-channels (96 gate rows); Wh slice
// in registers. 384 threads = 6 waves = 3 gates x 2 K-halves, each a
// 16x32x384 MFMA chain; K-halves reduced in LDS; gate threads (tid<256) do
// pointwise GRU math + publish h.
//
// This round's levers (vs R5's measured 980us):
//  1. SINGLE-POLLER: only wave 5 (tid>=320 -- the wave with NO xz prefetch
//     loads outstanding, so its poll's vmcnt drain is free) polls the
//     group's flag line; 5 other waves park at a barrier. 6x less LLC poll
//     traffic, and one wave's 24-lane poll of a single 128B line coalesces
//     into ~1 request.
//  2. xz prefetch AFTER publish: pre-publish vmcnt(0) drains only the 8B
//     h-store, not a ~900cy HBM load.
//  3. Every spin has an iteration GUARD: on overflow we proceed (wrong data,
//     test fails diagnosably) instead of hanging the container.
// ---------------------------------------------------------------------------
__global__ __launch_bounds__(384) void recur3_kernel(
    const u16* __restrict__ xz, const float* __restrict__ Wh,
    const float* __restrict__ bh, u16* __restrict__ hsx, int* flags)
{
    __shared__ float hzs[2 * 8 * 96];
    const int tid  = threadIdx.x;
    const int bid  = blockIdx.x;
    const int g    = bid / PWG;
    const int s    = bid - g * PWG;
    const int lane = tid & 63;
    const int wv   = tid >> 6;          // 0..5
    const int kh   = wv & 1;            // K half (384 each)
    const int np   = wv >> 1;           // gate index 0..2
    const int fr   = lane & 15, fq = lane >> 4;
    const int c0   = s * 32;            // this WG's h-channel base
    const int B0   = g * 8;             // this group's batch base

    // one-time: invalidate stale (previous graph-replay) cache lines
    __builtin_amdgcn_fence(__ATOMIC_ACQUIRE, "agent");

    // ---- one-time: Wh slice -> B-frags in registers (bf16) ----
    bf16x8 bfrag[2][12];
#pragma unroll
    for (int j = 0; j < 2; ++j) {
        int row = np * 768 + c0 + j * 16 + fr;
        const float* wp = Wh + (size_t)row * 768 + kh * 384 + fq * 8;
#pragma unroll
        for (int kk = 0; kk < 12; ++kk) {
            float4 f0 = *(const float4*)(wp + kk * 32);
            float4 f1 = *(const float4*)(wp + kk * 32 + 4);
            bf16x8 b;
            b[0] = (short)f2bf(f0.x); b[1] = (short)f2bf(f0.y);
            b[2] = (short)f2bf(f0.z); b[3] = (short)f2bf(f0.w);
            b[4] = (short)f2bf(f1.x); b[5] = (short)f2bf(f1.y);
            b[6] = (short)f2bf(f1.z); b[7] = (short)f2bf(f1.w);
            bfrag[j][kk] = b;
        }
    }

    // gate-phase constants: thread t<256 -> (batch gb, channel gi)
    const int gb = tid >> 5, gi = tid & 31;
    const int gc = c0 + gi;
    float bh0 = 0.f, bh1 = 0.f, bh2 = 0.f, hold = 0.f;
    if (tid < 256) { bh0 = bh[gc]; bh1 = bh[768 + gc]; bh2 = bh[1536 + gc]; }

    // one flag line per group; lane l polls slot l%24 (coalesces to ~1 req)
    const int pl = lane % PWG;
    int* const myflag      = &flags[g * FLINE + s];
    const int* const pollp = &flags[g * FLINE + pl];

    // preload xz for step 0
    float xgn0 = 0.f, xgn1 = 0.f, xgn2 = 0.f;
    if (tid < 256) {
        size_t xoff = (size_t)(B0 + gb) * 2304 + gc;
        xgn0 = bf2f(xz[xoff]);
        xgn1 = bf2f(xz[xoff + 768]);
        xgn2 = bf2f(xz[xoff + 1536]);
    }

    for (int n = 0; n < NSTEP; ++n) {
        const float xg0 = xgn0, xg1 = xgn1, xg2 = xgn2;   // prefetched

        f32x4 acc0 = (f32x4){0.f, 0.f, 0.f, 0.f};
        f32x4 acc1 = (f32x4){0.f, 0.f, 0.f, 0.f};

        if (n > 0) {
            // wave 5 polls; everyone else parks at the barrier
            if (tid >= 320) {
                int guard = 0;
                for (;;) {
                    int v = agent_load(pollp);
                    if (__all(v >= n)) break;
                    if (++guard > GUARD) break;   // hang insurance
                    __builtin_amdgcn_s_sleep(1);
                }
            }
            __syncthreads();

            // A-frags: h[n-1][B0+fr][k]; rows fr>=8 zero (M=8 padded to 16).
            // Plain loads are safe: each hsx address is write-once/read-once
            // per replay and the entry acquire fence dropped older copies.
            const u16* ap = hsx + (size_t)(n - 1) * HSTEP
                                + (size_t)(B0 + fr) * 768 + kh * 384 + fq * 8;
            const bool arow = fr < 8;
#pragma unroll
            for (int kk = 0; kk < 12; ++kk) {
                bf16x8 a = arow ? *(const bf16x8*)(ap + kk * 32)
                                : (bf16x8){0, 0, 0, 0, 0, 0, 0, 0};
                acc0 = __builtin_amdgcn_mfma_f32_16x16x32_bf16(a, bfrag[0][kk], acc0, 0, 0, 0);
                acc1 = __builtin_amdgcn_mfma_f32_16x16x32_bf16(a, bfrag[1][kk], acc1, 0, 0, 0);
            }
        }

        // partial h_zrn (per K-half) -> LDS
#pragma unroll
        for (int r = 0; r < 4; ++r) {
            int b = fq * 4 + r;
            if (b < 8) {
                hzs[(kh * 8 + b) * 96 + np * 32 + fr]      = acc0[r];
                hzs[(kh * 8 + b) * 96 + np * 32 + 16 + fr] = acc1[r];
            }
        }
        __syncthreads();

        if (tid < 256) {
            float h0 = hzs[gb * 96 + gi]      + hzs[(8 + gb) * 96 + gi]      + bh0;
            float h1 = hzs[gb * 96 + 32 + gi] + hzs[(8 + gb) * 96 + 32 + gi] + bh1;
            float h2 = hzs[gb * 96 + 64 + gi] + hzs[(8 + gb) * 96 + 64 + gi] + bh2;
            float z   = 1.f / (1.f + __expf(-(xg0 + h0)));
            float rr2 = 1.f / (1.f + __expf(-(xg1 + h1)));
            float pre = xg2 + rr2 * h2;
            float e2  = __expf(-2.f * pre);
            float nc  = (1.f - e2) / (1.f + e2);
            float hnew = (1.f - z) * nc + z * hold;
            hold = hnew;

            // pack 4 channels -> one 8B agent store per 4 threads
            u16 hv = f2bf(hnew);
            u32 other = ((u32)__shfl_xor((int)hv, 1, 64)) & 0xffffu;
            u32 v01 = (u32)hv | (other << 16);
            u32 v23 = (u32)__shfl_xor((int)v01, 2, 64);
            if ((tid & 3) == 0) {
                u64 q = (u64)v01 | ((u64)v23 << 32);
                size_t ofs = (size_t)n * HSTEP + (size_t)(B0 + gb) * 768 + gc;
                __hip_atomic_store((u64*)(hsx + ofs), q,
                                   __ATOMIC_RELAXED, __HIP_MEMORY_SCOPE_AGENT);
            }
        }
        // drain ONLY the h-store (no loads outstanding), then publish
        asm volatile("s_waitcnt vmcnt(0)" ::: "memory");
        __syncthreads();
        if (tid == 0) agent_store(myflag, n + 1);

        // prefetch next step's xz AFTER the publish: its latency overlaps
        // the next poll instead of delaying the flag everyone waits on.
        if (tid < 256) {
            int np1 = (n + 1 < NSTEP) ? n + 1 : NSTEP - 1;
            size_t xoff = ((size_t)np1 * 64 + (B0 + gb)) * 2304 + gc;
            xgn0 = bf2f(xz[xoff]);
            xgn1 = bf2f(xz[xoff + 768]);
            xgn2 = bf2f(xz[xoff + 1536]);
        }
    }
}

// ---------------------------------------------------------------------------
extern "C" void kernel_launch(void* const* d_in, const int* in_sizes, int n_in,
                              void* d_out, int out_size, void* d_ws, size_t ws_size,
                              hipStream_t stream)
{
    const float* x  = (const float*)d_in[0];
    const float* Wx = (const float*)d_in[1];
    const float* bx = (const float*)d_in[2];
    const float* Wh = (const float*)d_in[3];
    const float* bh = (const float*)d_in[4];
    const float* Wp = (const float*)d_in[5];
    float* out = (float*)d_out;

    char* ws = (char*)d_ws;
    size_t off = 0;
    auto wsalloc = [&](size_t bytes) -> void* {
        void* p = ws + off;
        off += (bytes + 255) & ~(size_t)255;
        return p;
    };
    u16* xb   = (u16*)wsalloc(9633792ull * 2);            // x bf16 [12544][768]
    u16* wxb  = (u16*)wsalloc(1769472ull * 2);            // Wx bf16 [2304][768]
    u16* wpb  = (u16*)wsalloc(589824ull * 2);             // Wp bf16 [768][768]
    u16* xzrn = (u16*)wsalloc(196ull * 64 * 2304 * 2);    // [n][b][3C] bf16
    u16* hsx  = (u16*)wsalloc(196ull * 64 * 768 * 2);     // [n][b][C] bf16
    int* flags = (int*)wsalloc(1024);                     // 8 group flag lines

    // 1) converts (+ zero flag lines)
    cvt_kernel<<<11712, 256, 0, stream>>>(
        (const float4*)x, (const float4*)Wx, (const float4*)Wp,
        (u32*)xb, (u32*)wxb, (u32*)wpb, flags);

    // 2) x_zrn = seq @ Wx^T + bx  ->  [n][b][3C] bf16
    gemm_bt<1><<<dim3(18, 98), 256, 0, stream>>>(xb, wxb, bx, (void*)xzrn);

    // 3) cooperative batch-split recurrence (8 groups x 24 WGs, static)
    {
        const u16* a0 = xzrn; const float* a1 = Wh; const float* a2 = bh;
        u16* a3 = hsx; int* a4 = flags;
        void* args[5] = { &a0, &a1, &a2, &a3, &a4 };
        hipLaunchCooperativeKernel((void*)recur3_kernel, dim3(NGRP * PWG),
                                   dim3(384), args, 0, stream);
    }

    // 4) y = hsx @ Wp^T -> d_out fp32 (rows m = n*64+b, remapped on store)
    gemm_bt<0><<<dim3(6, 98), 256, 0, stream>>>(hsx, wpb, nullptr, (void*)out);
}